// Round 4
// baseline (265.890 us; speedup 1.0000x reference)
//
#include <hip/hip_runtime.h>

#define H1F 16

// ---------------------------------------------------------------------------
// proj1: per-node projections xl = x @ Wl1^T, xr = x @ Wr1^T + b1
// ---------------------------------------------------------------------------
__global__ void proj1_kernel(const float* __restrict__ x,
                             const float* __restrict__ Wl1,
                             const float* __restrict__ Wr1,
                             const float* __restrict__ b1,
                             float* __restrict__ xl,
                             float* __restrict__ xr,
                             int N) {
    __shared__ float xs[16][65];
    __shared__ float wl[16][65];
    __shared__ float wr[16][65];

    int t = threadIdx.x;
    int nodeBase = blockIdx.x * 16;

    for (int i = t; i < 16 * 64; i += 256) {
        int r = i >> 6, c = i & 63;
        wl[r][c] = Wl1[i];
        wr[r][c] = Wr1[i];
        int gn = nodeBase + r;
        xs[r][c] = (gn < N) ? x[(size_t)gn * 64 + c] : 0.0f;
    }
    __syncthreads();

    int n = t >> 4;
    int f = t & 15;
    int gn = nodeBase + n;
    if (gn >= N) return;

    float al = 0.0f, ar = 0.0f;
#pragma unroll
    for (int k = 0; k < 64; ++k) {
        float xv = xs[n][k];
        al += xv * wl[f][k];
        ar += xv * wr[f][k];
    }
    xl[(size_t)gn * H1F + f] = al;
    xr[(size_t)gn * H1F + f] = ar + b1[f];
}

// ---------------------------------------------------------------------------
// count: degv[dst]++ (fire-and-forget atomics into 400KB, L2-resident)
// ---------------------------------------------------------------------------
__global__ void count_kernel(const int* __restrict__ ei,
                             int* __restrict__ degv,
                             int E) {
    int e = blockIdx.x * blockDim.x + threadIdx.x;
    if (e >= E) return;
    atomicAdd(degv + ei[E + e], 1);
}

// ---------------------------------------------------------------------------
// scan (3 kernels): exclusive prefix sum of degv -> offp; cur = copy of offp
// ---------------------------------------------------------------------------
__global__ void scan_blocks(const int* __restrict__ degv,
                            int* __restrict__ offp,
                            int* __restrict__ bsum,
                            int N) {
    int i = blockIdx.x * 256 + threadIdx.x;
    int v = (i < N) ? degv[i] : 0;
    int lane = threadIdx.x & 63;
    int wid = threadIdx.x >> 6;           // 0..3
    int s = v;
#pragma unroll
    for (int d = 1; d < 64; d <<= 1) {
        int u = __shfl_up(s, d);
        if (lane >= d) s += u;
    }
    __shared__ int wsum[4];
    if (lane == 63) wsum[wid] = s;
    __syncthreads();
    int wofs = 0;
    for (int w = 0; w < wid; ++w) wofs += wsum[w];
    if (i < N) offp[i] = wofs + s - v;    // block-local exclusive
    if (threadIdx.x == 255) bsum[blockIdx.x] = wofs + s;
}

__global__ void scan_top(const int* __restrict__ bsum,
                         int* __restrict__ bpre,
                         int B) {
    // 1 block x 512 threads, each handles 4 entries -> B <= 2048
    int t = threadIdx.x;
    int k0 = t * 4;
    int a0 = (k0 + 0 < B) ? bsum[k0 + 0] : 0;
    int a1 = (k0 + 1 < B) ? bsum[k0 + 1] : 0;
    int a2 = (k0 + 2 < B) ? bsum[k0 + 2] : 0;
    int a3 = (k0 + 3 < B) ? bsum[k0 + 3] : 0;
    int tot = a0 + a1 + a2 + a3;

    int lane = t & 63;
    int wid = t >> 6;                     // 0..7
    int s = tot;
#pragma unroll
    for (int d = 1; d < 64; d <<= 1) {
        int u = __shfl_up(s, d);
        if (lane >= d) s += u;
    }
    __shared__ int wsum[8];
    if (lane == 63) wsum[wid] = s;
    __syncthreads();
    int wofs = 0;
    for (int w = 0; w < wid; ++w) wofs += wsum[w];
    int excl = wofs + s - tot;
    if (k0 + 0 < B) bpre[k0 + 0] = excl;
    if (k0 + 1 < B) bpre[k0 + 1] = excl + a0;
    if (k0 + 2 < B) bpre[k0 + 2] = excl + a0 + a1;
    if (k0 + 3 < B) bpre[k0 + 3] = excl + a0 + a1 + a2;
}

__global__ void scan_add(int* __restrict__ offp,
                         const int* __restrict__ bpre,
                         int* __restrict__ cur,
                         int N) {
    int i = blockIdx.x * 256 + threadIdx.x;
    if (i >= N) return;
    int o = offp[i] + bpre[blockIdx.x];
    offp[i] = o;
    cur[i] = o;
}

// ---------------------------------------------------------------------------
// place: csr[atomicAdd(cur[dst])] = src  (compact 6.4MB region)
// ---------------------------------------------------------------------------
__global__ void place_kernel(const int* __restrict__ ei,
                             int* __restrict__ cur,
                             int* __restrict__ csr,
                             int E) {
    int e = blockIdx.x * blockDim.x + threadIdx.x;
    if (e >= E) return;
    int src = ei[e];
    int dst = ei[E + e];
    int pos = atomicAdd(cur + dst, 1);
    csr[pos] = src;
}

// ---------------------------------------------------------------------------
// gather1 (+finalize1 fused): 16 lanes per node, lane = feature.
// ---------------------------------------------------------------------------
__global__ void gather1_kernel(const int* __restrict__ csr,
                               const int* __restrict__ offp,
                               const int* __restrict__ degv,
                               const float* __restrict__ xl,
                               const float* __restrict__ xr,
                               const float* __restrict__ Wl2,
                               const float* __restrict__ Wr2,
                               const float* __restrict__ b2,
                               float* __restrict__ hl2,
                               float* __restrict__ outp,
                               int N) {
    int t = blockIdx.x * blockDim.x + threadIdx.x;
    int node = t >> 4;
    int f = t & 15;
    if (node >= N) return;

    int d = degv[node];
    const int* row = csr + offp[node];

    float s = 0.0f;
    int j = 0;
    for (; j + 4 <= d; j += 4) {
        int s0 = row[j], s1 = row[j + 1], s2 = row[j + 2], s3 = row[j + 3];
        s += xl[(size_t)s0 * H1F + f];
        s += xl[(size_t)s1 * H1F + f];
        s += xl[(size_t)s2 * H1F + f];
        s += xl[(size_t)s3 * H1F + f];
    }
    for (; j < d; ++j) s += xl[(size_t)row[j] * H1F + f];

    float inv = 1.0f / fmaxf((float)d, 1.0f);
    float h = fmaxf(s * inv + xr[(size_t)node * H1F + f], 0.0f);
    float pl = h * Wl2[f];
    float pr = h * Wr2[f];
#pragma unroll
    for (int off = 8; off; off >>= 1) {
        pl += __shfl_xor(pl, off);
        pr += __shfl_xor(pr, off);
    }
    if (f == 0) {
        hl2[node] = pl;
        outp[node] = pr + b2[0];
    }
}

// ---------------------------------------------------------------------------
// gather2 (+finalize2 fused): 4 lanes per node.
// ---------------------------------------------------------------------------
__global__ void gather2_kernel(const int* __restrict__ csr,
                               const int* __restrict__ offp,
                               const int* __restrict__ degv,
                               const float* __restrict__ hl2,
                               const float* __restrict__ outp,
                               float* __restrict__ out,
                               int N) {
    int t = blockIdx.x * blockDim.x + threadIdx.x;
    int node = t >> 2;
    int l = t & 3;
    if (node >= N) return;

    int d = degv[node];
    const int* row = csr + offp[node];

    float s = 0.0f;
    for (int j = l; j < d; j += 4) s += hl2[row[j]];
    s += __shfl_xor(s, 1);
    s += __shfl_xor(s, 2);
    if (l == 0) out[node] = s / fmaxf((float)d, 1.0f) + outp[node];
}

extern "C" void kernel_launch(void* const* d_in, const int* in_sizes, int n_in,
                              void* d_out, int out_size, void* d_ws, size_t ws_size,
                              hipStream_t stream) {
    const float* x   = (const float*)d_in[0];
    const int*   ei  = (const int*)d_in[1];   // [2, E] int32
    const float* Wl1 = (const float*)d_in[2];
    const float* Wr1 = (const float*)d_in[3];
    const float* b1  = (const float*)d_in[4];
    const float* Wl2 = (const float*)d_in[5];
    const float* Wr2 = (const float*)d_in[6];
    const float* b2  = (const float*)d_in[7];
    float* out = (float*)d_out;

    int N = in_sizes[0] / 64;
    int E = in_sizes[1] / 2;
    int B = (N + 255) / 256;   // scan blocks (<=2048 supported by scan_top)

    int*   degv = (int*)d_ws;                      // N
    int*   offp = degv + N;                        // N
    int*   cur  = offp + N;                        // N
    int*   bsum = cur + N;                         // B
    int*   bpre = bsum + B;                        // B
    int*   csr  = bpre + B;                        // E
    float* xl   = (float*)(csr + E);               // 16N
    float* xr   = xl + (size_t)16 * N;             // 16N
    float* hl2  = xr + (size_t)16 * N;             // N
    float* outp = hl2 + N;                         // N

    (void)hipMemsetAsync(degv, 0, (size_t)N * sizeof(int), stream);

    proj1_kernel<<<(N + 15) / 16, 256, 0, stream>>>(x, Wl1, Wr1, b1, xl, xr, N);

    count_kernel<<<(E + 255) / 256, 256, 0, stream>>>(ei, degv, E);

    scan_blocks<<<B, 256, 0, stream>>>(degv, offp, bsum, N);
    scan_top<<<1, 512, 0, stream>>>(bsum, bpre, B);
    scan_add<<<B, 256, 0, stream>>>(offp, bpre, cur, N);

    place_kernel<<<(E + 255) / 256, 256, 0, stream>>>(ei, cur, csr, E);

    gather1_kernel<<<((N * 16) + 255) / 256, 256, 0, stream>>>(
        csr, offp, degv, xl, xr, Wl2, Wr2, b2, hl2, outp, N);

    gather2_kernel<<<((N * 4) + 255) / 256, 256, 0, stream>>>(
        csr, offp, degv, hl2, outp, out, N);
}